// Round 9
// baseline (21.096 us; speedup 1.0000x reference)
//
#include <hip/hip_runtime.h>

// ---------------------------------------------------------------------------
// FFT_Conv_Layer == 3x3 "same" spatial conv with flipped REAL filter plane:
//   out[b,o,y,x] = sum_{i,ky,kx} filts[0,i,o,ky,kx,0] * img[b,i,y+1-ky,x+1-kx]
//
// Ladder: R2 = 22.54us (256thr, wave 64x32, 2 waves/SIMD)
//         R5 = 27.0us  (1 wave/SIMD: TLP matters)
//         R7 = 21.24us (+XCD swizzle, -1.3us)
//         R8 = 21.07us (staging de-serialization: neutral — already batched)
// Floors sum to ~8-10us => bubble-bound. Waves/SIMD = threads/65536; at
// 32 out/thread it's pinned to 2. R9: 16 out/thread (wave tile 32x32, 2x2
// frags, SAME 0.5 ds_read/MFMA ratio, SAME traffic/redundancy as R2) ->
// 512 blocks x 512thr(8 waves), 2 blk/CU, 4 waves/SIMD. Pure TLP lever.
// ---------------------------------------------------------------------------

typedef _Float16 f16x8 __attribute__((ext_vector_type(8)));
typedef float    f32x4 __attribute__((ext_vector_type(4)));

#define NB 16
#define NC 64
#define NH 64
#define NW 64
#define CHUNKS 528                 // 66 xp positions * 8 channel-chunks per slab
#define SLAB_BYTES (CHUNKS * 16)   // 8448 B per image row slab
#define WF_HALFS (9 * 2 * 4 * 64 * 8)  // taps * kc * n * lane * elem = 36864

// ---------------------------------------------------------------------------
// prep_w: filts [1][inC][outC][3][3][2] f32 -> per-fragment f16 weights
//   Wf[t][kc][n][lane][e] = filts[0][ i=kc*32+(l/16)*8+e ][ o=n*16+l%16 ][ky][kx][0]
// ---------------------------------------------------------------------------
__global__ __launch_bounds__(256) void prep_w(const float* __restrict__ filts,
                                              _Float16* __restrict__ wf) {
    const int f = blockIdx.x * 256 + threadIdx.x;
    if (f >= WF_HALFS) return;
    const int e  = f & 7;
    const int l  = (f >> 3) & 63;
    const int n  = (f >> 9) & 3;
    const int kc = (f >> 11) & 1;
    const int t  = f >> 12;              // 0..8
    const int i  = kc * 32 + (l >> 4) * 8 + e;
    const int o  = n * 16 + (l & 15);
    const int ky = t / 3, kx = t % 3;
    wf[f] = (_Float16)filts[(((i * 64 + o) * 3 + ky) * 3 + kx) * 2];
}

// ---------------------------------------------------------------------------
// conv_direct: 512 blocks (XCD-swizzled) = (b, 2-row group), 8 waves (512 thr).
//   Staging: wave w stages (slab = w>>1, channel-half = w&1): 32 f32 loads
//     into regs, cvt f16, 4 swizzled ds_write_b128. Pads by half==0, l<16.
//     chunk = xp*8 + (ci^(xp&7)) -> conflict-free b128 ops.
//   Compute: wave w = (row = w>>2, xh = (w>>1)&1, oh = w&1) owns a 32x32
//     tile: 2x2 16x16 frags. K-loop = 3ky*3kx*2kc: 2 A ds_reads + 2 B global
//     + 4 MFMA per step. 4 waves/SIMD hide the per-step dependency stalls.
//   C/D layout (m89/m91-verified): o = n*16+(lane&15), x = m*16+(lane>>4)*4+j
// ---------------------------------------------------------------------------
__global__ __launch_bounds__(512, 4) void conv_direct(const float* __restrict__ imgs,
                                                      const _Float16* __restrict__ wf,
                                                      float* __restrict__ out) {
    __shared__ uint4 ldsb[4 * SLAB_BYTES / 16];   // 33,792 B
    char* lds = reinterpret_cast<char*>(ldsb);
    // bijective XCD swizzle (512 = 8*64): XCD x gets swz in [64x, 64x+64)
    // = images {2x, 2x+1} -> staged row re-reads are XCD-local L2 hits.
    const int bid = blockIdx.x;
    const int swz = ((bid & 7) << 6) | (bid >> 3);
    const int b   = swz >> 5;
    const int y0  = (swz & 31) << 1;     // first output row of this block
    const int tid = threadIdx.x;
    const int w   = tid >> 6;            // wave 0..7
    const int l   = tid & 63;
    const int h   = l >> 4;              // k-chunk lane group
    const int r   = l & 15;              // A-row / B-col within fragment

    // ---- stage: wave w -> slab w>>1 (img row y0+(w>>1)-1), ch-half w&1 ----
    {
        const int sl   = w >> 1;
        const int half = w & 1;
        const int y    = y0 + sl - 1;
        const bool yv  = ((unsigned)y < (unsigned)NH);
        char* slab = lds + sl * SLAB_BYTES;

        // pads: 16 zero chunks (xp = 0 and 65, 8 ci each), by half 0 lanes
        if (half == 0 && l < 16) {
            const int ci  = l >> 1;
            const int xp2 = (l & 1) ? 65 : 0;
            const int c2  = xp2 * 8 + (ci ^ (xp2 & 7));
            f16x8 z;
            #pragma unroll
            for (int k = 0; k < 8; ++k) z[k] = (_Float16)0.f;
            *reinterpret_cast<f16x8*>(slab + c2 * 16) = z;
        }

        // pass 1: 32 channel loads (c = half*32 + j) into registers
        float f[32];
        if (yv) {
            const float* src = imgs + (((size_t)(b * NC + half * 32)) * NH + y) * NW + l;
            #pragma unroll
            for (int j = 0; j < 32; ++j)
                f[j] = src[(size_t)j * NH * NW];
        } else {
            #pragma unroll
            for (int j = 0; j < 32; ++j) f[j] = 0.f;
        }

        // pass 2: cvt + 4 swizzled ds_write_b128 (ci = half*4 .. half*4+3)
        const int xp = l + 1;                          // lane covers x = l
        #pragma unroll
        for (int cj = 0; cj < 4; ++cj) {
            const int ci = half * 4 + cj;
            f16x8 v;
            #pragma unroll
            for (int k = 0; k < 8; ++k) v[k] = (_Float16)f[cj * 8 + k];
            const int chunk = xp * 8 + (ci ^ (xp & 7));
            *reinterpret_cast<f16x8*>(slab + chunk * 16) = v;
        }
    }
    __syncthreads();

    const int row = w >> 2;              // output row offset within group
    const int xh  = (w >> 1) & 1;        // x half (0..1)
    const int oh  = w & 1;               // outC half (0..1)

    f32x4 acc[2][2];
    #pragma unroll
    for (int m = 0; m < 2; ++m)
        #pragma unroll
        for (int n = 0; n < 2; ++n)
            acc[m][n] = f32x4{0.f, 0.f, 0.f, 0.f};

    #pragma unroll
    for (int ky = 0; ky < 3; ++ky) {
        const char* slab = lds + (row + 2 - ky) * SLAB_BYTES;   // rs in 0..3
        #pragma unroll
        for (int kx = 0; kx < 3; ++kx) {
            const _Float16* wft = wf + (size_t)(ky * 3 + kx) * (2 * 4 * 64 * 8);
            #pragma unroll
            for (int kc = 0; kc < 2; ++kc) {
                f16x8 a[2], bb[2];
                #pragma unroll
                for (int m = 0; m < 2; ++m) {
                    const int xp = xh * 32 + m * 16 + r + 2 - kx;  // 0..65
                    const int chunk = xp * 8 + (((kc << 2) + h) ^ (xp & 7));
                    a[m] = *reinterpret_cast<const f16x8*>(slab + chunk * 16);
                }
                #pragma unroll
                for (int n = 0; n < 2; ++n)
                    bb[n] = *reinterpret_cast<const f16x8*>(
                        wft + ((size_t)((kc << 2) + (oh * 2 + n)) * 64 + l) * 8);
                #pragma unroll
                for (int m = 0; m < 2; ++m)
                    #pragma unroll
                    for (int n = 0; n < 2; ++n)
                        acc[m][n] = __builtin_amdgcn_mfma_f32_16x16x32_f16(a[m], bb[n], acc[m][n], 0, 0, 0);
            }
        }
    }

    const int y = y0 + row;
    #pragma unroll
    for (int m = 0; m < 2; ++m) {
        const int x0 = xh * 32 + m * 16 + h * 4;
        #pragma unroll
        for (int n = 0; n < 2; ++n) {
            const int o = oh * 32 + n * 16 + r;
            *reinterpret_cast<f32x4*>(out + (((size_t)(b * 64 + o) * 64 + y) * 64) + x0) = acc[m][n];
        }
    }
}

extern "C" void kernel_launch(void* const* d_in, const int* in_sizes, int n_in,
                              void* d_out, int out_size, void* d_ws, size_t ws_size,
                              hipStream_t stream) {
    const float* imgs  = (const float*)d_in[0];   // [16][64][64][64] f32
    const float* filts = (const float*)d_in[1];   // [1][64][64][3][3][2] f32
    float* out = (float*)d_out;                   // [16][64][64][64] f32
    _Float16* wfb = (_Float16*)d_ws;              // 73,728 B only

    hipLaunchKernelGGL(prep_w, dim3((WF_HALFS + 255) / 256), dim3(256), 0, stream, filts, wfb);
    hipLaunchKernelGGL(conv_direct, dim3(NB * 32), dim3(512), 0, stream, imgs, wfb, out);
}